// Round 2
// baseline (2077.049 us; speedup 1.0000x reference)
//
#include <hip/hip_runtime.h>

// ---------------------------------------------------------------------------
// LSTM autoencoder: B=32, F=128, T=2400, H=256, SEG=24, S=100.
// Strategy: f16 weights + v_dot2_f32_f16 (f32 accum), fp32 cell state.
//  - outer encoder/decoder: weight-streaming from L2 (amortized over 10 seqs/block)
//  - inner encoder/decoder: weights register+LDS resident (1 block per sequence)
//  - input projections precomputed as batched GEMMs with biases folded in
// ---------------------------------------------------------------------------

#define B_    32
#define F_    128
#define T_    2400
#define H_    256
#define SEG_  24
#define S_    100
#define NSEQ_ 3200

using v2h = __attribute__((ext_vector_type(2))) _Float16;
using v4h = __attribute__((ext_vector_type(4))) _Float16;
using v8h = __attribute__((ext_vector_type(8))) _Float16;

#ifndef __has_builtin
#define __has_builtin(x) 0
#endif

__device__ __forceinline__ float fdot2f(v2h a, v2h b, float c) {
#if __has_builtin(__builtin_amdgcn_fdot2)
  return __builtin_amdgcn_fdot2(a, b, c, false);
#else
  return c + (float)a[0] * (float)b[0] + (float)a[1] * (float)b[1];
#endif
}

// extract half2 pair e from a vector (constant-folds under #pragma unroll)
__device__ __forceinline__ v2h ext8(v8h v, int e) {
  v2h r; r[0] = v[2 * e]; r[1] = v[2 * e + 1]; return r;
}
__device__ __forceinline__ v2h ext4(v4h v, int e) {
  v2h r; r[0] = v[2 * e]; r[1] = v[2 * e + 1]; return r;
}

__device__ __forceinline__ float sigm(float x) { return 1.f / (1.f + __expf(-x)); }
__device__ __forceinline__ float tanh_f(float x) { return 1.f - 2.f / (__expf(2.f * x) + 1.f); }

// ---------------------------------------------------------------------------
// Weight prep: build transposed half2 weights dst[k2][g] from row-major fp32
// [W_ih (G x K1); W_hh (G x K2src)] stacked along K. n = K2tot * G.
// ---------------------------------------------------------------------------
__global__ void k_wt2(v2h* __restrict__ dst, const float* __restrict__ w1, int K1,
                      const float* __restrict__ w2, int K2src, int G, int n) {
  int idx = blockIdx.x * 256 + threadIdx.x;
  if (idx >= n) return;
  int k2 = idx / G, g = idx - k2 * G;
  int k = 2 * k2;
  float v0, v1;
  if (k < K1) {
    v0 = w1[(size_t)g * K1 + k];
    v1 = w1[(size_t)g * K1 + k + 1];
  } else {
    int kk = k - K1;
    v0 = w2[(size_t)g * K2src + kk];
    v1 = w2[(size_t)g * K2src + kk + 1];
  }
  v2h r;
  r[0] = (_Float16)v0;
  r[1] = (_Float16)v1;
  dst[idx] = r;
}

// fp32 -> f16 elementwise (row-major weights for the inner kernels)
__global__ void k_f16(_Float16* __restrict__ dst, const float* __restrict__ src, int n) {
  int i = blockIdx.x * 256 + threadIdx.x;
  if (i < n) dst[i] = (_Float16)src[i];
}

// ---------------------------------------------------------------------------
// Input transpose: inp (B,F,T) fp32 -> xT[(b*2400+tau)][f] f16  (tau = s*24+t)
// ---------------------------------------------------------------------------
__global__ void k_tin(const float* __restrict__ inp, _Float16* __restrict__ xT) {
  __shared__ float tile[32][33];
  int b = blockIdx.z, f0 = blockIdx.y * 32, t0 = blockIdx.x * 32;
  int tx = threadIdx.x, ty = threadIdx.y;
#pragma unroll
  for (int r = 0; r < 4; ++r) {
    int f = f0 + ty + 8 * r;
    tile[ty + 8 * r][tx] = inp[((size_t)b * F_ + f) * T_ + t0 + tx];
  }
  __syncthreads();
#pragma unroll
  for (int r = 0; r < 4; ++r) {
    int tau = t0 + ty + 8 * r;
    xT[((size_t)b * T_ + tau) * F_ + f0 + tx] = (_Float16)tile[tx][ty + 8 * r];
  }
}

// Output transpose: rec[(b*2400+tau)][f] fp32 -> out (B,F,T) fp32
__global__ void k_tout(const float* __restrict__ rec, float* __restrict__ out) {
  __shared__ float tile[32][33];
  int b = blockIdx.z, f0 = blockIdx.y * 32, t0 = blockIdx.x * 32;
  int tx = threadIdx.x, ty = threadIdx.y;
#pragma unroll
  for (int r = 0; r < 4; ++r) {
    int tau = t0 + ty + 8 * r;
    tile[ty + 8 * r][tx] = rec[((size_t)b * T_ + tau) * F_ + f0 + tx];
  }
  __syncthreads();
#pragma unroll
  for (int r = 0; r < 4; ++r) {
    int f = f0 + ty + 8 * r;
    out[((size_t)b * F_ + f) * T_ + t0 + tx] = tile[tx][ty + 8 * r];
  }
}

// ---------------------------------------------------------------------------
// Outer encoder: 320 blocks x 10 seqs, 256 threads (thread g owns h-index g,
// gate rows g, g+256, g+512, g+768). a2[s] = [x_t (128) | h (256)] f16.
// Weights: wt2 [192 k2][1024 g] streamed from L2. Output: final c -> cst.
// ---------------------------------------------------------------------------
__global__ __launch_bounds__(256) void k_outer_enc(
    const v2h* __restrict__ wt2, const v2h* __restrict__ xT2,
    const float* __restrict__ bih, const float* __restrict__ bhh,
    float* __restrict__ cst) {
  constexpr int NS = 10;
  __shared__ __align__(16) _Float16 a2[NS][384];
  const int tid = threadIdx.x;
  const int seq0 = blockIdx.x * NS;
  float bias[4];
#pragma unroll
  for (int q = 0; q < 4; ++q) bias[q] = bih[tid + 256 * q] + bhh[tid + 256 * q];
  float c[NS];
#pragma unroll
  for (int s = 0; s < NS; ++s) c[s] = 0.f;
  for (int idx = tid; idx < NS * 256; idx += 256) {  // zero h region
    int s = idx >> 8, e = idx & 255;
    a2[s][128 + e] = (_Float16)0.f;
  }
  float acc[NS][4];
  for (int t = 0; t < SEG_; ++t) {
    // stage x_t for all NS seqs (64 half2 per seq)
    for (int idx = tid; idx < NS * 64; idx += 256) {
      int s = idx >> 6, k2 = idx & 63;
      ((v2h*)&a2[s][0])[k2] = xT2[((size_t)(seq0 + s) * SEG_ + t) * 64 + k2];
    }
    __syncthreads();
#pragma unroll
    for (int s = 0; s < NS; ++s)
#pragma unroll
      for (int q = 0; q < 4; ++q) acc[s][q] = bias[q];
    const v2h* wp = wt2 + tid;
#pragma unroll 2
    for (int k2 = 0; k2 < 192; ++k2) {
      v2h w0 = wp[0], w1 = wp[256], w2 = wp[512], w3 = wp[768];
      wp += 1024;
#pragma unroll
      for (int s = 0; s < NS; ++s) {
        v2h a = ((const v2h*)&a2[s][0])[k2];
        acc[s][0] = fdot2f(w0, a, acc[s][0]);
        acc[s][1] = fdot2f(w1, a, acc[s][1]);
        acc[s][2] = fdot2f(w2, a, acc[s][2]);
        acc[s][3] = fdot2f(w3, a, acc[s][3]);
      }
    }
    __syncthreads();
#pragma unroll
    for (int s = 0; s < NS; ++s) {
      float gi = sigm(acc[s][0]), gf = sigm(acc[s][1]);
      float gg = tanh_f(acc[s][2]), go = sigm(acc[s][3]);
      c[s] = gf * c[s] + gi * gg;
      float h = go * tanh_f(c[s]);
      a2[s][128 + tid] = (_Float16)h;
    }
  }
#pragma unroll
  for (int s = 0; s < NS; ++s) cst[(size_t)(seq0 + s) * H_ + tid] = c[s];
}

// ---------------------------------------------------------------------------
// Batched input projection: out[M][G] = A[M][256] @ wt2[128][G] + b1 + b2.
// 16 rows per block, 256 threads, GT = G/256 gates per thread.
// ---------------------------------------------------------------------------
template <int GT>
__global__ __launch_bounds__(256) void k_proj(
    const float* __restrict__ A, const v2h* __restrict__ wt2,
    const float* __restrict__ b1, const float* __restrict__ b2,
    float* __restrict__ out) {
  constexpr int G = GT * 256;
  __shared__ __align__(16) _Float16 a2[16][256];
  const int tid = threadIdx.x;
  const size_t row0 = (size_t)blockIdx.x * 16;
  for (int idx = tid; idx < 16 * 256; idx += 256) {
    int r = idx >> 8, k = idx & 255;
    a2[r][k] = (_Float16)A[(row0 + (size_t)r) * 256 + k];
  }
  __syncthreads();
  float acc[16][GT];
#pragma unroll
  for (int r = 0; r < 16; ++r)
#pragma unroll
    for (int q = 0; q < GT; ++q) acc[r][q] = 0.f;
  const v2h* wp = wt2 + tid;
#pragma unroll 2
  for (int k2 = 0; k2 < 128; ++k2) {
    v2h w[GT];
#pragma unroll
    for (int q = 0; q < GT; ++q) w[q] = wp[256 * q];
    wp += G;
#pragma unroll
    for (int r = 0; r < 16; ++r) {
      v2h a = ((const v2h*)&a2[r][0])[k2];
#pragma unroll
      for (int q = 0; q < GT; ++q) acc[r][q] = fdot2f(w[q], a, acc[r][q]);
    }
  }
#pragma unroll
  for (int q = 0; q < GT; ++q) {
    float bias = b1[tid + 256 * q] + b2[tid + 256 * q];
#pragma unroll
    for (int r = 0; r < 16; ++r)
      out[(row0 + (size_t)r) * G + tid + 256 * q] = acc[r][q] + bias;
  }
}

// ---------------------------------------------------------------------------
// Inner LSTM (encoder/decoder): 1 block per batch element, 512 threads.
// Thread pair (2p, 2p+1) owns h-index p; each lane holds a 128-wide K-half of
// gate rows i,f,g in VGPRs (192 regs) and the o-row in padded LDS (133 KB).
// xw holds precomputed input projection (+biases). One shfl_xor reduce/pair.
// ---------------------------------------------------------------------------
__global__ __launch_bounds__(512) void k_inner(
    const _Float16* __restrict__ whh,  // [1024][256] row-major f16
    const float* __restrict__ xw, long xw_seq_stride, long xw_t_stride, int T,
    float* __restrict__ h_out,   // [B*T][256] or nullptr
    float* __restrict__ c_out) { // [B][256] or nullptr
  __shared__ __align__(16) _Float16 ah[H_];
  __shared__ __align__(16) _Float16 wo[H_][260];  // o-row, padded vs bank conflicts
  const int t_ = threadIdx.x;
  const int p = t_ >> 1;
  const int hf = t_ & 1;
  const int b = blockIdx.x;

  v8h wv[3][16];  // rows i,f,g ; this lane's 128-wide K-half
#pragma unroll
  for (int r = 0; r < 3; ++r) {
    const v8h* src = (const v8h*)(whh + ((size_t)(H_ * r + p)) * H_ + hf * 128);
#pragma unroll
    for (int q = 0; q < 16; ++q) wv[r][q] = src[q];
  }
  {  // stage o-row into LDS
    const v4h* src = (const v4h*)(whh + ((size_t)(H_ * 3 + p)) * H_ + hf * 128);
    v4h* dst = (v4h*)&wo[p][hf * 128];
#pragma unroll
    for (int q = 0; q < 32; ++q) dst[q] = src[q];
  }
  if (t_ < H_) ah[t_] = (_Float16)0.f;
  float c = 0.f;
  __syncthreads();

  for (int t = 0; t < T; ++t) {
    const float* xwp = xw + (size_t)b * xw_seq_stride + (size_t)t * xw_t_stride;
    float x0 = xwp[p], x1 = xwp[H_ + p], x2 = xwp[2 * H_ + p], x3 = xwp[3 * H_ + p];
    float a0 = 0.f, a1 = 0.f, a2 = 0.f, a3 = 0.f;
    const v8h* A8 = ((const v8h*)ah) + hf * 16;
    const v4h* O4 = (const v4h*)&wo[p][hf * 128];
#pragma unroll
    for (int q = 0; q < 16; ++q) {
      v8h av = A8[q];
      v8h w0v = wv[0][q], w1v = wv[1][q], w2v = wv[2][q];
      v4h o0 = O4[2 * q], o1 = O4[2 * q + 1];
#pragma unroll
      for (int e = 0; e < 4; ++e) {
        v2h ap = ext8(av, e);
        a0 = fdot2f(ext8(w0v, e), ap, a0);
        a1 = fdot2f(ext8(w1v, e), ap, a1);
        a2 = fdot2f(ext8(w2v, e), ap, a2);
        v2h op = (e < 2) ? ext4(o0, e) : ext4(o1, e - 2);
        a3 = fdot2f(op, ap, a3);
      }
    }
    a0 += __shfl_xor(a0, 1);
    a1 += __shfl_xor(a1, 1);
    a2 += __shfl_xor(a2, 1);
    a3 += __shfl_xor(a3, 1);
    float gi = sigm(a0 + x0);
    float gf = sigm(a1 + x1);
    float gg = tanh_f(a2 + x2);
    float go = sigm(a3 + x3);
    c = gf * c + gi * gg;
    float h = go * tanh_f(c);
    __syncthreads();
    if (hf == 0) {
      ah[p] = (_Float16)h;
      if (h_out) h_out[((size_t)b * T + t) * H_ + p] = h;
    }
    __syncthreads();
  }
  if (c_out && hf == 0) c_out[(size_t)b * H_ + p] = c;
}

// ---------------------------------------------------------------------------
// Outer decoder: 320 blocks x 10 seqs, 128 threads (thread g owns h-index g,
// gate rows g, g+128, g+256, g+384). Input projection xw constant per seq.
// Writes every h to rec[(seq*24+t)][128].
// ---------------------------------------------------------------------------
__global__ __launch_bounds__(128) void k_outer_dec(
    const v2h* __restrict__ wt2hh,  // [64][512]
    const float* __restrict__ xw,   // [3200][512] (biases folded)
    float* __restrict__ rec) {      // [3200*24][128]
  constexpr int NS = 10;
  __shared__ __align__(16) _Float16 ahh[NS][128];
  const int g = threadIdx.x;
  const int seq0 = blockIdx.x * NS;
  float xwr[NS][4];
#pragma unroll
  for (int s = 0; s < NS; ++s)
#pragma unroll
    for (int r = 0; r < 4; ++r)
      xwr[s][r] = xw[(size_t)(seq0 + s) * 512 + g + 128 * r];
  float c[NS];
#pragma unroll
  for (int s = 0; s < NS; ++s) c[s] = 0.f;
  for (int idx = g; idx < NS * 128; idx += 128) {
    int s = idx >> 7, e = idx & 127;
    ahh[s][e] = (_Float16)0.f;
  }
  __syncthreads();
  float acc[NS][4];
  for (int t = 0; t < SEG_; ++t) {
#pragma unroll
    for (int s = 0; s < NS; ++s)
#pragma unroll
      for (int r = 0; r < 4; ++r) acc[s][r] = xwr[s][r];
    const v2h* wp = wt2hh + g;
#pragma unroll 2
    for (int k2 = 0; k2 < 64; ++k2) {
      v2h w0 = wp[0], w1 = wp[128], w2 = wp[256], w3 = wp[384];
      wp += 512;
#pragma unroll
      for (int s = 0; s < NS; ++s) {
        v2h a = ((const v2h*)&ahh[s][0])[k2];
        acc[s][0] = fdot2f(w0, a, acc[s][0]);
        acc[s][1] = fdot2f(w1, a, acc[s][1]);
        acc[s][2] = fdot2f(w2, a, acc[s][2]);
        acc[s][3] = fdot2f(w3, a, acc[s][3]);
      }
    }
    __syncthreads();
#pragma unroll
    for (int s = 0; s < NS; ++s) {
      float gi = sigm(acc[s][0]), gf = sigm(acc[s][1]);
      float gg = tanh_f(acc[s][2]), go = sigm(acc[s][3]);
      c[s] = gf * c[s] + gi * gg;
      float h = go * tanh_f(c[s]);
      ahh[s][g] = (_Float16)h;
      rec[((size_t)(seq0 + s) * SEG_ + t) * 128 + g] = h;
    }
    __syncthreads();
  }
}

// ---------------------------------------------------------------------------
extern "C" void kernel_launch(void* const* d_in, const int* in_sizes, int n_in,
                              void* d_out, int out_size, void* d_ws, size_t ws_size,
                              hipStream_t stream) {
  const float* inp    = (const float*)d_in[0];
  const float* oe_wih = (const float*)d_in[1];
  const float* oe_whh = (const float*)d_in[2];
  const float* oe_bih = (const float*)d_in[3];
  const float* oe_bhh = (const float*)d_in[4];
  const float* ie_wih = (const float*)d_in[5];
  const float* ie_whh = (const float*)d_in[6];
  const float* ie_bih = (const float*)d_in[7];
  const float* ie_bhh = (const float*)d_in[8];
  const float* id_wih = (const float*)d_in[9];
  const float* id_whh = (const float*)d_in[10];
  const float* id_bih = (const float*)d_in[11];
  const float* id_bhh = (const float*)d_in[12];
  const float* od_wih = (const float*)d_in[13];
  const float* od_whh = (const float*)d_in[14];
  const float* od_bih = (const float*)d_in[15];
  const float* od_bhh = (const float*)d_in[16];

  char* ws = (char*)d_ws;
  _Float16* xT     = (_Float16*)(ws + 0);         // 76800*128 f16 = 19,660,800
  v2h* wt2_oe      = (v2h*)(ws + 19660800);       // 192*1024*4   =    786,432
  float* cst       = (float*)(ws + 20447232);     // 3200*256*4   =  3,276,800
  v2h* wt2_ie      = (v2h*)(ws + 23724032);       // 128*1024*4   =    524,288
  float* xw_ie     = (float*)(ws + 24248320);     // 3200*1024*4  = 13,107,200
  _Float16* whh_ie = (_Float16*)(ws + 37355520);  // 262144 f16   =    524,288
  float* bott      = (float*)(ws + 37879808);     // 32*256*4     =     32,768
  v2h* wt2_id      = (v2h*)(ws + 37912576);       //              =    524,288
  float* xw_id     = (float*)(ws + 38436864);     // 32*1024*4    =    131,072
  _Float16* whh_id = (_Float16*)(ws + 38567936);  //              =    524,288
  float* dec       = (float*)(ws + 39092224);     // 3200*256*4   =  3,276,800
  v2h* wt2_odih    = (v2h*)(ws + 42369024);       // 128*512*4    =    262,144
  float* xw_od     = (float*)(ws + 42631168);     // 3200*512*4   =  6,553,600
  v2h* wt2_odhh    = (v2h*)(ws + 49184768);       // 64*512*4     =    131,072
  float* rec       = (float*)(ws + 49315840);     // 76800*128*4  = 39,321,600  (end 88.6 MB)

  // --- weight prep ---
  k_wt2<<<dim3(768), dim3(256), 0, stream>>>(wt2_oe, oe_wih, 128, oe_whh, 256, 1024, 192 * 1024);
  k_wt2<<<dim3(512), dim3(256), 0, stream>>>(wt2_ie, ie_wih, 256, nullptr, 0, 1024, 128 * 1024);
  k_wt2<<<dim3(512), dim3(256), 0, stream>>>(wt2_id, id_wih, 256, nullptr, 0, 1024, 128 * 1024);
  k_wt2<<<dim3(256), dim3(256), 0, stream>>>(wt2_odih, od_wih, 256, nullptr, 0, 512, 128 * 512);
  k_wt2<<<dim3(128), dim3(256), 0, stream>>>(wt2_odhh, od_whh, 128, nullptr, 0, 512, 64 * 512);
  k_f16<<<dim3(1024), dim3(256), 0, stream>>>(whh_ie, ie_whh, 262144);
  k_f16<<<dim3(1024), dim3(256), 0, stream>>>(whh_id, id_whh, 262144);

  // --- pipeline ---
  k_tin<<<dim3(75, 4, 32), dim3(32, 8), 0, stream>>>(inp, xT);
  k_outer_enc<<<dim3(320), dim3(256), 0, stream>>>(wt2_oe, (const v2h*)xT, oe_bih, oe_bhh, cst);
  k_proj<4><<<dim3(200), dim3(256), 0, stream>>>(cst, wt2_ie, ie_bih, ie_bhh, xw_ie);
  k_inner<<<dim3(32), dim3(512), 0, stream>>>(whh_ie, xw_ie, (long)S_ * 1024, 1024, S_, nullptr, bott);
  k_proj<4><<<dim3(2), dim3(256), 0, stream>>>(bott, wt2_id, id_bih, id_bhh, xw_id);
  k_inner<<<dim3(32), dim3(512), 0, stream>>>(whh_id, xw_id, 1024, 0, S_, dec, nullptr);
  k_proj<2><<<dim3(200), dim3(256), 0, stream>>>(dec, wt2_odih, od_bih, od_bhh, xw_od);
  k_outer_dec<<<dim3(320), dim3(128), 0, stream>>>(wt2_odhh, xw_od, rec);
  k_tout<<<dim3(75, 4, 32), dim3(32, 8), 0, stream>>>(rec, (float*)d_out);

  (void)in_sizes; (void)n_in; (void)out_size; (void)ws_size;
}

// Round 3
// 1300.912 us; speedup vs baseline: 1.5966x; 1.5966x over previous
//
#include <hip/hip_runtime.h>

// ---------------------------------------------------------------------------
// LSTM autoencoder: B=32, F=128, T=2400, H=256, SEG=24, S=100.
//  - outer encoder: MFMA f16 16x16x32, W prepacked fragment-major, streamed
//    from L2 each step; c-state persistent in VGPRs; h round-trips via LDS.
//  - outer decoder: fdot2 weight-streaming (next target)
//  - inner encoder/decoder: weights register+LDS resident (1 block per seq)
//  - input projections precomputed as batched GEMMs with biases folded in
// ---------------------------------------------------------------------------

#define B_    32
#define F_    128
#define T_    2400
#define H_    256
#define SEG_  24
#define S_    100
#define NSEQ_ 3200

using v2h = __attribute__((ext_vector_type(2))) _Float16;
using v4h = __attribute__((ext_vector_type(4))) _Float16;
using v8h = __attribute__((ext_vector_type(8))) _Float16;
using v4f = __attribute__((ext_vector_type(4))) float;

#ifndef __has_builtin
#define __has_builtin(x) 0
#endif

__device__ __forceinline__ float fdot2f(v2h a, v2h b, float c) {
#if __has_builtin(__builtin_amdgcn_fdot2)
  return __builtin_amdgcn_fdot2(a, b, c, false);
#else
  return c + (float)a[0] * (float)b[0] + (float)a[1] * (float)b[1];
#endif
}

// extract half2 pair e from a vector (constant-folds under #pragma unroll)
__device__ __forceinline__ v2h ext8(v8h v, int e) {
  v2h r; r[0] = v[2 * e]; r[1] = v[2 * e + 1]; return r;
}
__device__ __forceinline__ v2h ext4(v4h v, int e) {
  v2h r; r[0] = v[2 * e]; r[1] = v[2 * e + 1]; return r;
}

__device__ __forceinline__ float sigm(float x) { return 1.f / (1.f + __expf(-x)); }
__device__ __forceinline__ float tanh_f(float x) { return 1.f - 2.f / (__expf(2.f * x) + 1.f); }

// ---------------------------------------------------------------------------
// Weight prep: build transposed half2 weights dst[k2][g] from row-major fp32
// [W_ih (G x K1); W_hh (G x K2src)] stacked along K. n = K2tot * G.
// ---------------------------------------------------------------------------
__global__ void k_wt2(v2h* __restrict__ dst, const float* __restrict__ w1, int K1,
                      const float* __restrict__ w2, int K2src, int G, int n) {
  int idx = blockIdx.x * 256 + threadIdx.x;
  if (idx >= n) return;
  int k2 = idx / G, g = idx - k2 * G;
  int k = 2 * k2;
  float v0, v1;
  if (k < K1) {
    v0 = w1[(size_t)g * K1 + k];
    v1 = w1[(size_t)g * K1 + k + 1];
  } else {
    int kk = k - K1;
    v0 = w2[(size_t)g * K2src + kk];
    v1 = w2[(size_t)g * K2src + kk + 1];
  }
  v2h r;
  r[0] = (_Float16)v0;
  r[1] = (_Float16)v1;
  dst[idx] = r;
}

// fp32 -> f16 elementwise (row-major weights for the inner kernels)
__global__ void k_f16(_Float16* __restrict__ dst, const float* __restrict__ src, int n) {
  int i = blockIdx.x * 256 + threadIdx.x;
  if (i < n) dst[i] = (_Float16)src[i];
}

// ---------------------------------------------------------------------------
// Outer-encoder W prepack into B-fragment-major layout:
// dst[((kc*64 + nt)*64 + lane)] = v8h { W[col][k0..k0+7] }, col = nt*16 +
// (lane&15), k0 = kc*32 + (lane>>4)*8; W[col][k] = k<128 ? wih[col][k]
// : whh[col][k-128].  12 k-chunks x 64 n-tiles.
// ---------------------------------------------------------------------------
__global__ void k_wpack_oe(v8h* __restrict__ dst, const float* __restrict__ wih,
                           const float* __restrict__ whh) {
  int idx = blockIdx.x * 256 + threadIdx.x;  // 0..49151
  if (idx >= 12 * 64 * 64) return;
  int lane = idx & 63;
  int nt = (idx >> 6) & 63;
  int kc = idx >> 12;
  int col = nt * 16 + (lane & 15);
  int k0 = kc * 32 + (lane >> 4) * 8;
  v8h r;
#pragma unroll
  for (int j = 0; j < 8; ++j) {
    int k = k0 + j;
    float v = (k < 128) ? wih[(size_t)col * 128 + k] : whh[(size_t)col * 256 + (k - 128)];
    r[j] = (_Float16)v;
  }
  dst[idx] = r;
}

// ---------------------------------------------------------------------------
// Input transpose: inp (B,F,T) fp32 -> xT[(b*2400+tau)][f] f16  (tau = s*24+t)
// ---------------------------------------------------------------------------
__global__ void k_tin(const float* __restrict__ inp, _Float16* __restrict__ xT) {
  __shared__ float tile[32][33];
  int b = blockIdx.z, f0 = blockIdx.y * 32, t0 = blockIdx.x * 32;
  int tx = threadIdx.x, ty = threadIdx.y;
#pragma unroll
  for (int r = 0; r < 4; ++r) {
    int f = f0 + ty + 8 * r;
    tile[ty + 8 * r][tx] = inp[((size_t)b * F_ + f) * T_ + t0 + tx];
  }
  __syncthreads();
#pragma unroll
  for (int r = 0; r < 4; ++r) {
    int tau = t0 + ty + 8 * r;
    xT[((size_t)b * T_ + tau) * F_ + f0 + tx] = (_Float16)tile[tx][ty + 8 * r];
  }
}

// Output transpose: rec[(b*2400+tau)][f] fp32 -> out (B,F,T) fp32
__global__ void k_tout(const float* __restrict__ rec, float* __restrict__ out) {
  __shared__ float tile[32][33];
  int b = blockIdx.z, f0 = blockIdx.y * 32, t0 = blockIdx.x * 32;
  int tx = threadIdx.x, ty = threadIdx.y;
#pragma unroll
  for (int r = 0; r < 4; ++r) {
    int tau = t0 + ty + 8 * r;
    tile[ty + 8 * r][tx] = rec[((size_t)b * T_ + tau) * F_ + f0 + tx];
  }
  __syncthreads();
#pragma unroll
  for (int r = 0; r < 4; ++r) {
    int f = f0 + ty + 8 * r;
    out[((size_t)b * F_ + f) * T_ + t0 + tx] = tile[tx][ty + 8 * r];
  }
}

// ---------------------------------------------------------------------------
// Outer encoder, MFMA version. Grid 100 blocks x 512 threads (8 waves).
// Block: M=32 seqs. Wave w owns gate cols {g*256 + w*32 + jt*16 + c}
// (g=0..3, jt=0..1, c=lane&15) -> h-cols w*32..w*32+31 stay wave-local.
// Per step: gates[32x1024] = A[32x384] @ W[384x1024] via 16x16x32 f16 MFMA,
// A=[x_t|h] staged in LDS (row pitch 392 halves = 784B, conflict-free),
// W streamed fragment-major from L2 (768 KB/block/step, double-buffered).
// c-state in VGPRs across steps; final c -> cst.
// ---------------------------------------------------------------------------
__global__ __launch_bounds__(512, 2) void k_outer_enc_mfma(
    const v8h* __restrict__ wpack,    // [12][64][64] v8h
    const _Float16* __restrict__ xT,  // [(seq*24+t)*128 + f]
    const float* __restrict__ bih, const float* __restrict__ bhh,
    float* __restrict__ cst) {        // [3200][256] fp32
  __shared__ __align__(16) _Float16 a2[32][392];
  const int tid = threadIdx.x;
  const int w = tid >> 6;
  const int lane = tid & 63;
  const int cI = lane & 15;
  const int q = lane >> 4;
  const int seq0 = blockIdx.x * 32;

  // biases for this lane's 8 (g,jt) columns
  float bias[4][2];
#pragma unroll
  for (int g = 0; g < 4; ++g)
#pragma unroll
    for (int jt = 0; jt < 2; ++jt) {
      int col = g * 256 + w * 32 + jt * 16 + cI;
      bias[g][jt] = bih[col] + bhh[col];
    }

  // zero h region of A
  for (int i = tid; i < 32 * 256; i += 512) a2[i >> 8][128 + (i & 255)] = (_Float16)0.f;
  // stage x(t=0): thread -> (row = tid>>4, 16B chunk = tid&15)
  {
    int row = tid >> 4, ch = tid & 15;
    v8h xv = ((const v8h*)(xT + ((size_t)(seq0 + row) * SEG_ + 0) * F_))[ch];
    *(v8h*)(&a2[row][ch * 8]) = xv;
  }
  __syncthreads();

  float cs[2][2][4];
#pragma unroll
  for (int mt = 0; mt < 2; ++mt)
#pragma unroll
    for (int jt = 0; jt < 2; ++jt)
#pragma unroll
      for (int r = 0; r < 4; ++r) cs[mt][jt][r] = 0.f;

  // local n -> global n-tile: nt = (n>>1)*16 + w*2 + (n&1)
  for (int t = 0; t < SEG_; ++t) {
    v4f C[2][8];
#pragma unroll
    for (int mt = 0; mt < 2; ++mt)
#pragma unroll
      for (int n = 0; n < 8; ++n) {
        v4f z = {0.f, 0.f, 0.f, 0.f};
        C[mt][n] = z;
      }
    v8h Bf[2][8];
#pragma unroll
    for (int n = 0; n < 8; ++n) {
      int nt = (n >> 1) * 16 + w * 2 + (n & 1);
      Bf[0][n] = wpack[(size_t)(0 * 64 + nt) * 64 + lane];
    }
#pragma unroll 2
    for (int kc = 0; kc < 12; ++kc) {
      int cur = kc & 1, nxt = cur ^ 1;
      if (kc < 11) {
#pragma unroll
        for (int n = 0; n < 8; ++n) {
          int nt = (n >> 1) * 16 + w * 2 + (n & 1);
          Bf[nxt][n] = wpack[(size_t)((kc + 1) * 64 + nt) * 64 + lane];
        }
      }
      v8h A0 = *(const v8h*)(&a2[0 * 16 + cI][kc * 32 + q * 8]);
      v8h A1 = *(const v8h*)(&a2[1 * 16 + cI][kc * 32 + q * 8]);
#pragma unroll
      for (int n = 0; n < 8; ++n) {
        C[0][n] = __builtin_amdgcn_mfma_f32_16x16x32_f16(A0, Bf[cur][n], C[0][n], 0, 0, 0);
        C[1][n] = __builtin_amdgcn_mfma_f32_16x16x32_f16(A1, Bf[cur][n], C[1][n], 0, 0, 0);
      }
    }
    __syncthreads();  // K-loop reads of a2 done
    // epilogue: gates -> c,h; write h into A's h-region
#pragma unroll
    for (int mt = 0; mt < 2; ++mt)
#pragma unroll
      for (int jt = 0; jt < 2; ++jt)
#pragma unroll
        for (int r = 0; r < 4; ++r) {
          float gi = sigm(C[mt][0 * 2 + jt][r] + bias[0][jt]);
          float gf = sigm(C[mt][1 * 2 + jt][r] + bias[1][jt]);
          float gg = tanh_f(C[mt][2 * 2 + jt][r] + bias[2][jt]);
          float go = sigm(C[mt][3 * 2 + jt][r] + bias[3][jt]);
          float cc = gf * cs[mt][jt][r] + gi * gg;
          cs[mt][jt][r] = cc;
          float h = go * tanh_f(cc);
          a2[mt * 16 + q * 4 + r][128 + w * 32 + jt * 16 + cI] = (_Float16)h;
        }
    if (t < SEG_ - 1) {  // stage x(t+1)
      int row = tid >> 4, ch = tid & 15;
      v8h xv = ((const v8h*)(xT + ((size_t)(seq0 + row) * SEG_ + (t + 1)) * F_))[ch];
      *(v8h*)(&a2[row][ch * 8]) = xv;
    }
    __syncthreads();  // h + x visible before next K-loop
  }
  // final c -> cst
#pragma unroll
  for (int mt = 0; mt < 2; ++mt)
#pragma unroll
    for (int jt = 0; jt < 2; ++jt)
#pragma unroll
      for (int r = 0; r < 4; ++r)
        cst[(size_t)(seq0 + mt * 16 + q * 4 + r) * H_ + w * 32 + jt * 16 + cI] = cs[mt][jt][r];
}

// ---------------------------------------------------------------------------
// Batched input projection: out[M][G] = A[M][256] @ wt2[128][G] + b1 + b2.
// 16 rows per block, 256 threads, GT = G/256 gates per thread.
// ---------------------------------------------------------------------------
template <int GT>
__global__ __launch_bounds__(256) void k_proj(
    const float* __restrict__ A, const v2h* __restrict__ wt2,
    const float* __restrict__ b1, const float* __restrict__ b2,
    float* __restrict__ out) {
  constexpr int G = GT * 256;
  __shared__ __align__(16) _Float16 a2[16][256];
  const int tid = threadIdx.x;
  const size_t row0 = (size_t)blockIdx.x * 16;
  for (int idx = tid; idx < 16 * 256; idx += 256) {
    int r = idx >> 8, k = idx & 255;
    a2[r][k] = (_Float16)A[(row0 + (size_t)r) * 256 + k];
  }
  __syncthreads();
  float acc[16][GT];
#pragma unroll
  for (int r = 0; r < 16; ++r)
#pragma unroll
    for (int q = 0; q < GT; ++q) acc[r][q] = 0.f;
  const v2h* wp = wt2 + tid;
#pragma unroll 2
  for (int k2 = 0; k2 < 128; ++k2) {
    v2h w[GT];
#pragma unroll
    for (int q = 0; q < GT; ++q) w[q] = wp[256 * q];
    wp += G;
#pragma unroll
    for (int r = 0; r < 16; ++r) {
      v2h a = ((const v2h*)&a2[r][0])[k2];
#pragma unroll
      for (int q = 0; q < GT; ++q) acc[r][q] = fdot2f(w[q], a, acc[r][q]);
    }
  }
#pragma unroll
  for (int q = 0; q < GT; ++q) {
    float bias = b1[tid + 256 * q] + b2[tid + 256 * q];
#pragma unroll
    for (int r = 0; r < 16; ++r)
      out[(row0 + (size_t)r) * G + tid + 256 * q] = acc[r][q] + bias;
  }
}

// ---------------------------------------------------------------------------
// Inner LSTM (encoder/decoder): 1 block per batch element, 512 threads.
// Thread pair (2p, 2p+1) owns h-index p; each lane holds a 128-wide K-half of
// gate rows i,f,g in VGPRs and the o-row in padded LDS.
// ---------------------------------------------------------------------------
__global__ __launch_bounds__(512) void k_inner(
    const _Float16* __restrict__ whh,  // [1024][256] row-major f16
    const float* __restrict__ xw, long xw_seq_stride, long xw_t_stride, int T,
    float* __restrict__ h_out,   // [B*T][256] or nullptr
    float* __restrict__ c_out) { // [B][256] or nullptr
  __shared__ __align__(16) _Float16 ah[H_];
  __shared__ __align__(16) _Float16 wo[H_][260];
  const int t_ = threadIdx.x;
  const int p = t_ >> 1;
  const int hf = t_ & 1;
  const int b = blockIdx.x;

  v8h wv[3][16];
#pragma unroll
  for (int r = 0; r < 3; ++r) {
    const v8h* src = (const v8h*)(whh + ((size_t)(H_ * r + p)) * H_ + hf * 128);
#pragma unroll
    for (int q = 0; q < 16; ++q) wv[r][q] = src[q];
  }
  {
    const v4h* src = (const v4h*)(whh + ((size_t)(H_ * 3 + p)) * H_ + hf * 128);
    v4h* dst = (v4h*)&wo[p][hf * 128];
#pragma unroll
    for (int q = 0; q < 32; ++q) dst[q] = src[q];
  }
  if (t_ < H_) ah[t_] = (_Float16)0.f;
  float c = 0.f;
  __syncthreads();

  for (int t = 0; t < T; ++t) {
    const float* xwp = xw + (size_t)b * xw_seq_stride + (size_t)t * xw_t_stride;
    float x0 = xwp[p], x1 = xwp[H_ + p], x2 = xwp[2 * H_ + p], x3 = xwp[3 * H_ + p];
    float a0 = 0.f, a1 = 0.f, a2 = 0.f, a3 = 0.f;
    const v8h* A8 = ((const v8h*)ah) + hf * 16;
    const v4h* O4 = (const v4h*)&wo[p][hf * 128];
#pragma unroll
    for (int q = 0; q < 16; ++q) {
      v8h av = A8[q];
      v8h w0v = wv[0][q], w1v = wv[1][q], w2v = wv[2][q];
      v4h o0 = O4[2 * q], o1 = O4[2 * q + 1];
#pragma unroll
      for (int e = 0; e < 4; ++e) {
        v2h ap = ext8(av, e);
        a0 = fdot2f(ext8(w0v, e), ap, a0);
        a1 = fdot2f(ext8(w1v, e), ap, a1);
        a2 = fdot2f(ext8(w2v, e), ap, a2);
        v2h op = (e < 2) ? ext4(o0, e) : ext4(o1, e - 2);
        a3 = fdot2f(op, ap, a3);
      }
    }
    a0 += __shfl_xor(a0, 1);
    a1 += __shfl_xor(a1, 1);
    a2 += __shfl_xor(a2, 1);
    a3 += __shfl_xor(a3, 1);
    float gi = sigm(a0 + x0);
    float gf = sigm(a1 + x1);
    float gg = tanh_f(a2 + x2);
    float go = sigm(a3 + x3);
    c = gf * c + gi * gg;
    float h = go * tanh_f(c);
    __syncthreads();
    if (hf == 0) {
      ah[p] = (_Float16)h;
      if (h_out) h_out[((size_t)b * T + t) * H_ + p] = h;
    }
    __syncthreads();
  }
  if (c_out && hf == 0) c_out[(size_t)b * H_ + p] = c;
}

// ---------------------------------------------------------------------------
// Outer decoder: 320 blocks x 10 seqs, 128 threads.
// ---------------------------------------------------------------------------
__global__ __launch_bounds__(128) void k_outer_dec(
    const v2h* __restrict__ wt2hh,  // [64][512]
    const float* __restrict__ xw,   // [3200][512] (biases folded)
    float* __restrict__ rec) {      // [3200*24][128]
  constexpr int NS = 10;
  __shared__ __align__(16) _Float16 ahh[NS][128];
  const int g = threadIdx.x;
  const int seq0 = blockIdx.x * NS;
  float xwr[NS][4];
#pragma unroll
  for (int s = 0; s < NS; ++s)
#pragma unroll
    for (int r = 0; r < 4; ++r)
      xwr[s][r] = xw[(size_t)(seq0 + s) * 512 + g + 128 * r];
  float c[NS];
#pragma unroll
  for (int s = 0; s < NS; ++s) c[s] = 0.f;
  for (int idx = g; idx < NS * 128; idx += 128) {
    int s = idx >> 7, e = idx & 127;
    ahh[s][e] = (_Float16)0.f;
  }
  __syncthreads();
  float acc[NS][4];
  for (int t = 0; t < SEG_; ++t) {
#pragma unroll
    for (int s = 0; s < NS; ++s)
#pragma unroll
      for (int r = 0; r < 4; ++r) acc[s][r] = xwr[s][r];
    const v2h* wp = wt2hh + g;
#pragma unroll 2
    for (int k2 = 0; k2 < 64; ++k2) {
      v2h w0 = wp[0], w1 = wp[128], w2 = wp[256], w3 = wp[384];
      wp += 512;
#pragma unroll
      for (int s = 0; s < NS; ++s) {
        v2h a = ((const v2h*)&ahh[s][0])[k2];
        acc[s][0] = fdot2f(w0, a, acc[s][0]);
        acc[s][1] = fdot2f(w1, a, acc[s][1]);
        acc[s][2] = fdot2f(w2, a, acc[s][2]);
        acc[s][3] = fdot2f(w3, a, acc[s][3]);
      }
    }
    __syncthreads();
#pragma unroll
    for (int s = 0; s < NS; ++s) {
      float gi = sigm(acc[s][0]), gf = sigm(acc[s][1]);
      float gg = tanh_f(acc[s][2]), go = sigm(acc[s][3]);
      c[s] = gf * c[s] + gi * gg;
      float h = go * tanh_f(c[s]);
      ahh[s][g] = (_Float16)h;
      rec[((size_t)(seq0 + s) * SEG_ + t) * 128 + g] = h;
    }
    __syncthreads();
  }
}

// ---------------------------------------------------------------------------
extern "C" void kernel_launch(void* const* d_in, const int* in_sizes, int n_in,
                              void* d_out, int out_size, void* d_ws, size_t ws_size,
                              hipStream_t stream) {
  const float* inp    = (const float*)d_in[0];
  const float* oe_wih = (const float*)d_in[1];
  const float* oe_whh = (const float*)d_in[2];
  const float* oe_bih = (const float*)d_in[3];
  const float* oe_bhh = (const float*)d_in[4];
  const float* ie_wih = (const float*)d_in[5];
  const float* ie_whh = (const float*)d_in[6];
  const float* ie_bih = (const float*)d_in[7];
  const float* ie_bhh = (const float*)d_in[8];
  const float* id_wih = (const float*)d_in[9];
  const float* id_whh = (const float*)d_in[10];
  const float* id_bih = (const float*)d_in[11];
  const float* id_bhh = (const float*)d_in[12];
  const float* od_wih = (const float*)d_in[13];
  const float* od_whh = (const float*)d_in[14];
  const float* od_bih = (const float*)d_in[15];
  const float* od_bhh = (const float*)d_in[16];

  char* ws = (char*)d_ws;
  _Float16* xT     = (_Float16*)(ws + 0);         // 76800*128 f16 = 19,660,800
  v8h* wpack_oe    = (v8h*)(ws + 19660800);       // 12*64*64*16  =    786,432
  float* cst       = (float*)(ws + 20447232);     // 3200*256*4   =  3,276,800
  v2h* wt2_ie      = (v2h*)(ws + 23724032);       // 128*1024*4   =    524,288
  float* xw_ie     = (float*)(ws + 24248320);     // 3200*1024*4  = 13,107,200
  _Float16* whh_ie = (_Float16*)(ws + 37355520);  // 262144 f16   =    524,288
  float* bott      = (float*)(ws + 37879808);     // 32*256*4     =     32,768
  v2h* wt2_id      = (v2h*)(ws + 37912576);       //              =    524,288
  float* xw_id     = (float*)(ws + 38436864);     // 32*1024*4    =    131,072
  _Float16* whh_id = (_Float16*)(ws + 38567936);  //              =    524,288
  float* dec       = (float*)(ws + 39092224);     // 3200*256*4   =  3,276,800
  v2h* wt2_odih    = (v2h*)(ws + 42369024);       // 128*512*4    =    262,144
  float* xw_od     = (float*)(ws + 42631168);     // 3200*512*4   =  6,553,600
  v2h* wt2_odhh    = (v2h*)(ws + 49184768);       // 64*512*4     =    131,072
  float* rec       = (float*)(ws + 49315840);     // 76800*128*4  = 39,321,600  (end 88.6 MB)

  // --- weight prep ---
  k_wpack_oe<<<dim3(192), dim3(256), 0, stream>>>(wpack_oe, oe_wih, oe_whh);
  k_wt2<<<dim3(512), dim3(256), 0, stream>>>(wt2_ie, ie_wih, 256, nullptr, 0, 1024, 128 * 1024);
  k_wt2<<<dim3(512), dim3(256), 0, stream>>>(wt2_id, id_wih, 256, nullptr, 0, 1024, 128 * 1024);
  k_wt2<<<dim3(256), dim3(256), 0, stream>>>(wt2_odih, od_wih, 256, nullptr, 0, 512, 128 * 512);
  k_wt2<<<dim3(128), dim3(256), 0, stream>>>(wt2_odhh, od_whh, 128, nullptr, 0, 512, 64 * 512);
  k_f16<<<dim3(1024), dim3(256), 0, stream>>>(whh_ie, ie_whh, 262144);
  k_f16<<<dim3(1024), dim3(256), 0, stream>>>(whh_id, id_whh, 262144);

  // --- pipeline ---
  k_tin<<<dim3(75, 4, 32), dim3(32, 8), 0, stream>>>(inp, xT);
  k_outer_enc_mfma<<<dim3(100), dim3(512), 0, stream>>>(wpack_oe, xT, oe_bih, oe_bhh, cst);
  k_proj<4><<<dim3(200), dim3(256), 0, stream>>>(cst, wt2_ie, ie_bih, ie_bhh, xw_ie);
  k_inner<<<dim3(32), dim3(512), 0, stream>>>(whh_ie, xw_ie, (long)S_ * 1024, 1024, S_, nullptr, bott);
  k_proj<4><<<dim3(2), dim3(256), 0, stream>>>(bott, wt2_id, id_bih, id_bhh, xw_id);
  k_inner<<<dim3(32), dim3(512), 0, stream>>>(whh_id, xw_id, 1024, 0, S_, dec, nullptr);
  k_proj<2><<<dim3(200), dim3(256), 0, stream>>>(dec, wt2_odih, od_bih, od_bhh, xw_od);
  k_outer_dec<<<dim3(320), dim3(128), 0, stream>>>(wt2_odhh, xw_od, rec);
  k_tout<<<dim3(75, 4, 32), dim3(32, 8), 0, stream>>>(rec, (float*)d_out);

  (void)in_sizes; (void)n_in; (void)out_size; (void)ws_size;
}

// Round 4
// 988.128 us; speedup vs baseline: 2.1020x; 1.3165x over previous
//
#include <hip/hip_runtime.h>

// ---------------------------------------------------------------------------
// LSTM autoencoder: B=32, F=128, T=2400, H=256, SEG=24, S=100.
//  - outer encoder: MFMA f16 16x16x32, W fragment-major streamed from L2,
//    double-buffered; c-state in VGPRs; h round-trips via LDS.
//  - outer decoder: MFMA f16, W_hh (64 VGPRs) + xw register-resident,
//    t-loop touches only LDS (A) + rec writes.
//  - inner encoder/decoder: weights register+LDS resident (1 block per seq)
//  - input projections precomputed as batched GEMMs with biases folded in
// ---------------------------------------------------------------------------

#define B_    32
#define F_    128
#define T_    2400
#define H_    256
#define SEG_  24
#define S_    100
#define NSEQ_ 3200

using v2h = __attribute__((ext_vector_type(2))) _Float16;
using v4h = __attribute__((ext_vector_type(4))) _Float16;
using v8h = __attribute__((ext_vector_type(8))) _Float16;
using v4f = __attribute__((ext_vector_type(4))) float;

#ifndef __has_builtin
#define __has_builtin(x) 0
#endif

__device__ __forceinline__ float fdot2f(v2h a, v2h b, float c) {
#if __has_builtin(__builtin_amdgcn_fdot2)
  return __builtin_amdgcn_fdot2(a, b, c, false);
#else
  return c + (float)a[0] * (float)b[0] + (float)a[1] * (float)b[1];
#endif
}

// extract half2 pair e from a vector (constant-folds under #pragma unroll)
__device__ __forceinline__ v2h ext8(v8h v, int e) {
  v2h r; r[0] = v[2 * e]; r[1] = v[2 * e + 1]; return r;
}
__device__ __forceinline__ v2h ext4(v4h v, int e) {
  v2h r; r[0] = v[2 * e]; r[1] = v[2 * e + 1]; return r;
}

__device__ __forceinline__ float sigm(float x) { return 1.f / (1.f + __expf(-x)); }
__device__ __forceinline__ float tanh_f(float x) { return 1.f - 2.f / (__expf(2.f * x) + 1.f); }

// ---------------------------------------------------------------------------
// Weight prep: build transposed half2 weights dst[k2][g] from row-major fp32
// [W_ih (G x K1); W_hh (G x K2src)] stacked along K. n = K2tot * G.
// ---------------------------------------------------------------------------
__global__ void k_wt2(v2h* __restrict__ dst, const float* __restrict__ w1, int K1,
                      const float* __restrict__ w2, int K2src, int G, int n) {
  int idx = blockIdx.x * 256 + threadIdx.x;
  if (idx >= n) return;
  int k2 = idx / G, g = idx - k2 * G;
  int k = 2 * k2;
  float v0, v1;
  if (k < K1) {
    v0 = w1[(size_t)g * K1 + k];
    v1 = w1[(size_t)g * K1 + k + 1];
  } else {
    int kk = k - K1;
    v0 = w2[(size_t)g * K2src + kk];
    v1 = w2[(size_t)g * K2src + kk + 1];
  }
  v2h r;
  r[0] = (_Float16)v0;
  r[1] = (_Float16)v1;
  dst[idx] = r;
}

// fp32 -> f16 elementwise (row-major weights for the inner kernels)
__global__ void k_f16(_Float16* __restrict__ dst, const float* __restrict__ src, int n) {
  int i = blockIdx.x * 256 + threadIdx.x;
  if (i < n) dst[i] = (_Float16)src[i];
}

// ---------------------------------------------------------------------------
// Outer-encoder W prepack into B-fragment-major layout:
// dst[((kc*64 + nt)*64 + lane)] = v8h { W[col][k0..k0+7] }, col = nt*16 +
// (lane&15), k0 = kc*32 + (lane>>4)*8; W[col][k] = k<128 ? wih[col][k]
// : whh[col][k-128].  12 k-chunks x 64 n-tiles.
// ---------------------------------------------------------------------------
__global__ void k_wpack_oe(v8h* __restrict__ dst, const float* __restrict__ wih,
                           const float* __restrict__ whh) {
  int idx = blockIdx.x * 256 + threadIdx.x;  // 0..49151
  if (idx >= 12 * 64 * 64) return;
  int lane = idx & 63;
  int nt = (idx >> 6) & 63;
  int kc = idx >> 12;
  int col = nt * 16 + (lane & 15);
  int k0 = kc * 32 + (lane >> 4) * 8;
  v8h r;
#pragma unroll
  for (int j = 0; j < 8; ++j) {
    int k = k0 + j;
    float v = (k < 128) ? wih[(size_t)col * 128 + k] : whh[(size_t)col * 256 + (k - 128)];
    r[j] = (_Float16)v;
  }
  dst[idx] = r;
}

// ---------------------------------------------------------------------------
// Outer-decoder W_hh prepack: dst[((kc*32 + nt)*64 + lane)] = v8h
// { whh[col][k0..k0+7] }, col = nt*16 + (lane&15), k0 = kc*32 + (lane>>4)*8.
// 4 k-chunks x 32 n-tiles (G=512, K=128).
// ---------------------------------------------------------------------------
__global__ void k_wpack_od(v8h* __restrict__ dst, const float* __restrict__ whh) {
  int idx = blockIdx.x * 256 + threadIdx.x;  // 0..8191
  if (idx >= 4 * 32 * 64) return;
  int lane = idx & 63;
  int nt = (idx >> 6) & 31;
  int kc = idx >> 11;
  int col = nt * 16 + (lane & 15);
  int k0 = kc * 32 + (lane >> 4) * 8;
  v8h r;
#pragma unroll
  for (int j = 0; j < 8; ++j) r[j] = (_Float16)whh[(size_t)col * 128 + k0 + j];
  dst[idx] = r;
}

// ---------------------------------------------------------------------------
// Input transpose: inp (B,F,T) fp32 -> xT[(b*2400+tau)][f] f16  (tau = s*24+t)
// ---------------------------------------------------------------------------
__global__ void k_tin(const float* __restrict__ inp, _Float16* __restrict__ xT) {
  __shared__ float tile[32][33];
  int b = blockIdx.z, f0 = blockIdx.y * 32, t0 = blockIdx.x * 32;
  int tx = threadIdx.x, ty = threadIdx.y;
#pragma unroll
  for (int r = 0; r < 4; ++r) {
    int f = f0 + ty + 8 * r;
    tile[ty + 8 * r][tx] = inp[((size_t)b * F_ + f) * T_ + t0 + tx];
  }
  __syncthreads();
#pragma unroll
  for (int r = 0; r < 4; ++r) {
    int tau = t0 + ty + 8 * r;
    xT[((size_t)b * T_ + tau) * F_ + f0 + tx] = (_Float16)tile[tx][ty + 8 * r];
  }
}

// Output transpose: rec[(b*2400+tau)][f] fp32 -> out (B,F,T) fp32
__global__ void k_tout(const float* __restrict__ rec, float* __restrict__ out) {
  __shared__ float tile[32][33];
  int b = blockIdx.z, f0 = blockIdx.y * 32, t0 = blockIdx.x * 32;
  int tx = threadIdx.x, ty = threadIdx.y;
#pragma unroll
  for (int r = 0; r < 4; ++r) {
    int tau = t0 + ty + 8 * r;
    tile[ty + 8 * r][tx] = rec[((size_t)b * T_ + tau) * F_ + f0 + tx];
  }
  __syncthreads();
#pragma unroll
  for (int r = 0; r < 4; ++r) {
    int f = f0 + ty + 8 * r;
    out[((size_t)b * F_ + f) * T_ + t0 + tx] = tile[tx][ty + 8 * r];
  }
}

// ---------------------------------------------------------------------------
// Outer encoder, MFMA version. Grid 100 blocks x 512 threads (8 waves).
// Block: M=32 seqs. Wave w owns gate cols {g*256 + w*32 + jt*16 + c}.
// A=[x_t|h] in LDS (pitch 392 halves, conflict-free); W streamed from L2
// fragment-major, double-buffered; c-state in VGPRs.
// ---------------------------------------------------------------------------
__global__ __launch_bounds__(512, 2) void k_outer_enc_mfma(
    const v8h* __restrict__ wpack,    // [12][64][64] v8h
    const _Float16* __restrict__ xT,  // [(seq*24+t)*128 + f]
    const float* __restrict__ bih, const float* __restrict__ bhh,
    float* __restrict__ cst) {        // [3200][256] fp32
  __shared__ __align__(16) _Float16 a2[32][392];
  const int tid = threadIdx.x;
  const int w = tid >> 6;
  const int lane = tid & 63;
  const int cI = lane & 15;
  const int q = lane >> 4;
  const int seq0 = blockIdx.x * 32;

  float bias[4][2];
#pragma unroll
  for (int g = 0; g < 4; ++g)
#pragma unroll
    for (int jt = 0; jt < 2; ++jt) {
      int col = g * 256 + w * 32 + jt * 16 + cI;
      bias[g][jt] = bih[col] + bhh[col];
    }

  for (int i = tid; i < 32 * 256; i += 512) a2[i >> 8][128 + (i & 255)] = (_Float16)0.f;
  {
    int row = tid >> 4, ch = tid & 15;
    v8h xv = ((const v8h*)(xT + ((size_t)(seq0 + row) * SEG_ + 0) * F_))[ch];
    *(v8h*)(&a2[row][ch * 8]) = xv;
  }
  __syncthreads();

  float cs[2][2][4];
#pragma unroll
  for (int mt = 0; mt < 2; ++mt)
#pragma unroll
    for (int jt = 0; jt < 2; ++jt)
#pragma unroll
      for (int r = 0; r < 4; ++r) cs[mt][jt][r] = 0.f;

  for (int t = 0; t < SEG_; ++t) {
    v4f C[2][8];
#pragma unroll
    for (int mt = 0; mt < 2; ++mt)
#pragma unroll
      for (int n = 0; n < 8; ++n) {
        v4f z = {0.f, 0.f, 0.f, 0.f};
        C[mt][n] = z;
      }
    v8h Bf[2][8];
#pragma unroll
    for (int n = 0; n < 8; ++n) {
      int nt = (n >> 1) * 16 + w * 2 + (n & 1);
      Bf[0][n] = wpack[(size_t)(0 * 64 + nt) * 64 + lane];
    }
#pragma unroll 2
    for (int kc = 0; kc < 12; ++kc) {
      int cur = kc & 1, nxt = cur ^ 1;
      if (kc < 11) {
#pragma unroll
        for (int n = 0; n < 8; ++n) {
          int nt = (n >> 1) * 16 + w * 2 + (n & 1);
          Bf[nxt][n] = wpack[(size_t)((kc + 1) * 64 + nt) * 64 + lane];
        }
      }
      v8h A0 = *(const v8h*)(&a2[0 * 16 + cI][kc * 32 + q * 8]);
      v8h A1 = *(const v8h*)(&a2[1 * 16 + cI][kc * 32 + q * 8]);
#pragma unroll
      for (int n = 0; n < 8; ++n) {
        C[0][n] = __builtin_amdgcn_mfma_f32_16x16x32_f16(A0, Bf[cur][n], C[0][n], 0, 0, 0);
        C[1][n] = __builtin_amdgcn_mfma_f32_16x16x32_f16(A1, Bf[cur][n], C[1][n], 0, 0, 0);
      }
    }
    __syncthreads();
#pragma unroll
    for (int mt = 0; mt < 2; ++mt)
#pragma unroll
      for (int jt = 0; jt < 2; ++jt)
#pragma unroll
        for (int r = 0; r < 4; ++r) {
          float gi = sigm(C[mt][0 * 2 + jt][r] + bias[0][jt]);
          float gf = sigm(C[mt][1 * 2 + jt][r] + bias[1][jt]);
          float gg = tanh_f(C[mt][2 * 2 + jt][r] + bias[2][jt]);
          float go = sigm(C[mt][3 * 2 + jt][r] + bias[3][jt]);
          float cc = gf * cs[mt][jt][r] + gi * gg;
          cs[mt][jt][r] = cc;
          float h = go * tanh_f(cc);
          a2[mt * 16 + q * 4 + r][128 + w * 32 + jt * 16 + cI] = (_Float16)h;
        }
    if (t < SEG_ - 1) {
      int row = tid >> 4, ch = tid & 15;
      v8h xv = ((const v8h*)(xT + ((size_t)(seq0 + row) * SEG_ + (t + 1)) * F_))[ch];
      *(v8h*)(&a2[row][ch * 8]) = xv;
    }
    __syncthreads();
  }
#pragma unroll
  for (int mt = 0; mt < 2; ++mt)
#pragma unroll
    for (int jt = 0; jt < 2; ++jt)
#pragma unroll
      for (int r = 0; r < 4; ++r)
        cst[(size_t)(seq0 + mt * 16 + q * 4 + r) * H_ + w * 32 + jt * 16 + cI] = cs[mt][jt][r];
}

// ---------------------------------------------------------------------------
// Outer decoder, MFMA version. Grid 100 blocks x 512 threads (8 waves).
// M=32 seqs, N=512 gates, K=128 (h only; xw precomputed per-seq constant).
// Wave w owns h-cols w*16..w*16+15 (gate cols g*128 + w*16 + cI, n-tile
// g*8+w). B = W_hh register-resident (16 v8h = 64 VGPRs) for all 24 steps;
// xw in registers. t-loop: 8 ds_read_b128 (A) + 32 MFMA per wave.
// A pitch 136 halves -> (4cI+4q)%32 uniform -> conflict-free.
// ---------------------------------------------------------------------------
__global__ __launch_bounds__(512, 2) void k_outer_dec_mfma(
    const v8h* __restrict__ wpack,  // [4][32][64] v8h
    const float* __restrict__ xw,   // [3200][512] (biases folded)
    float* __restrict__ rec) {      // [3200*24][128] fp32
  __shared__ __align__(16) _Float16 ah[32][136];
  const int tid = threadIdx.x;
  const int w = tid >> 6;
  const int lane = tid & 63;
  const int cI = lane & 15;
  const int q = lane >> 4;
  const int seq0 = blockIdx.x * 32;

  v8h Bf[4][4];  // [kc][g]
#pragma unroll
  for (int kc = 0; kc < 4; ++kc)
#pragma unroll
    for (int g = 0; g < 4; ++g)
      Bf[kc][g] = wpack[(size_t)(kc * 32 + g * 8 + w) * 64 + lane];

  float xwr[2][4][4];
#pragma unroll
  for (int mt = 0; mt < 2; ++mt)
#pragma unroll
    for (int r = 0; r < 4; ++r) {
      int row = seq0 + mt * 16 + q * 4 + r;
#pragma unroll
      for (int g = 0; g < 4; ++g)
        xwr[mt][r][g] = xw[(size_t)row * 512 + g * 128 + w * 16 + cI];
    }

  for (int i = tid; i < 32 * 128; i += 512) ah[i >> 7][i & 127] = (_Float16)0.f;
  __syncthreads();

  float cs[2][4];
#pragma unroll
  for (int mt = 0; mt < 2; ++mt)
#pragma unroll
    for (int r = 0; r < 4; ++r) cs[mt][r] = 0.f;

  for (int t = 0; t < SEG_; ++t) {
    v4f C[2][4];
#pragma unroll
    for (int mt = 0; mt < 2; ++mt)
#pragma unroll
      for (int g = 0; g < 4; ++g) {
        v4f z = {0.f, 0.f, 0.f, 0.f};
        C[mt][g] = z;
      }
#pragma unroll
    for (int kc = 0; kc < 4; ++kc) {
      v8h A0 = *(const v8h*)(&ah[0 * 16 + cI][kc * 32 + q * 8]);
      v8h A1 = *(const v8h*)(&ah[1 * 16 + cI][kc * 32 + q * 8]);
#pragma unroll
      for (int g = 0; g < 4; ++g) {
        C[0][g] = __builtin_amdgcn_mfma_f32_16x16x32_f16(A0, Bf[kc][g], C[0][g], 0, 0, 0);
        C[1][g] = __builtin_amdgcn_mfma_f32_16x16x32_f16(A1, Bf[kc][g], C[1][g], 0, 0, 0);
      }
    }
    __syncthreads();  // A reads done before h rewrite
#pragma unroll
    for (int mt = 0; mt < 2; ++mt)
#pragma unroll
      for (int r = 0; r < 4; ++r) {
        float gi = sigm(C[mt][0][r] + xwr[mt][r][0]);
        float gf = sigm(C[mt][1][r] + xwr[mt][r][1]);
        float gg = tanh_f(C[mt][2][r] + xwr[mt][r][2]);
        float go = sigm(C[mt][3][r] + xwr[mt][r][3]);
        float cc = gf * cs[mt][r] + gi * gg;
        cs[mt][r] = cc;
        float h = go * tanh_f(cc);
        int row = mt * 16 + q * 4 + r;
        ah[row][w * 16 + cI] = (_Float16)h;
        rec[((size_t)(seq0 + row) * SEG_ + t) * 128 + w * 16 + cI] = h;
      }
    __syncthreads();
  }
}

// ---------------------------------------------------------------------------
// Batched input projection: out[M][G] = A[M][256] @ wt2[128][G] + b1 + b2.
// ---------------------------------------------------------------------------
template <int GT>
__global__ __launch_bounds__(256) void k_proj(
    const float* __restrict__ A, const v2h* __restrict__ wt2,
    const float* __restrict__ b1, const float* __restrict__ b2,
    float* __restrict__ out) {
  constexpr int G = GT * 256;
  __shared__ __align__(16) _Float16 a2[16][256];
  const int tid = threadIdx.x;
  const size_t row0 = (size_t)blockIdx.x * 16;
  for (int idx = tid; idx < 16 * 256; idx += 256) {
    int r = idx >> 8, k = idx & 255;
    a2[r][k] = (_Float16)A[(row0 + (size_t)r) * 256 + k];
  }
  __syncthreads();
  float acc[16][GT];
#pragma unroll
  for (int r = 0; r < 16; ++r)
#pragma unroll
    for (int q = 0; q < GT; ++q) acc[r][q] = 0.f;
  const v2h* wp = wt2 + tid;
#pragma unroll 2
  for (int k2 = 0; k2 < 128; ++k2) {
    v2h w[GT];
#pragma unroll
    for (int q = 0; q < GT; ++q) w[q] = wp[256 * q];
    wp += G;
#pragma unroll
    for (int r = 0; r < 16; ++r) {
      v2h a = ((const v2h*)&a2[r][0])[k2];
#pragma unroll
      for (int q = 0; q < GT; ++q) acc[r][q] = fdot2f(w[q], a, acc[r][q]);
    }
  }
#pragma unroll
  for (int q = 0; q < GT; ++q) {
    float bias = b1[tid + 256 * q] + b2[tid + 256 * q];
#pragma unroll
    for (int r = 0; r < 16; ++r)
      out[(row0 + (size_t)r) * G + tid + 256 * q] = acc[r][q] + bias;
  }
}

// ---------------------------------------------------------------------------
// Inner LSTM (encoder/decoder): 1 block per batch element, 512 threads.
// ---------------------------------------------------------------------------
__global__ __launch_bounds__(512) void k_inner(
    const _Float16* __restrict__ whh,  // [1024][256] row-major f16
    const float* __restrict__ xw, long xw_seq_stride, long xw_t_stride, int T,
    float* __restrict__ h_out,   // [B*T][256] or nullptr
    float* __restrict__ c_out) { // [B][256] or nullptr
  __shared__ __align__(16) _Float16 ah[H_];
  __shared__ __align__(16) _Float16 wo[H_][260];
  const int t_ = threadIdx.x;
  const int p = t_ >> 1;
  const int hf = t_ & 1;
  const int b = blockIdx.x;

  v8h wv[3][16];
#pragma unroll
  for (int r = 0; r < 3; ++r) {
    const v8h* src = (const v8h*)(whh + ((size_t)(H_ * r + p)) * H_ + hf * 128);
#pragma unroll
    for (int q = 0; q < 16; ++q) wv[r][q] = src[q];
  }
  {
    const v4h* src = (const v4h*)(whh + ((size_t)(H_ * 3 + p)) * H_ + hf * 128);
    v4h* dst = (v4h*)&wo[p][hf * 128];
#pragma unroll
    for (int q = 0; q < 32; ++q) dst[q] = src[q];
  }
  if (t_ < H_) ah[t_] = (_Float16)0.f;
  float c = 0.f;
  __syncthreads();

  for (int t = 0; t < T; ++t) {
    const float* xwp = xw + (size_t)b * xw_seq_stride + (size_t)t * xw_t_stride;
    float x0 = xwp[p], x1 = xwp[H_ + p], x2 = xwp[2 * H_ + p], x3 = xwp[3 * H_ + p];
    float a0 = 0.f, a1 = 0.f, a2 = 0.f, a3 = 0.f;
    const v8h* A8 = ((const v8h*)ah) + hf * 16;
    const v4h* O4 = (const v4h*)&wo[p][hf * 128];
#pragma unroll
    for (int q = 0; q < 16; ++q) {
      v8h av = A8[q];
      v8h w0v = wv[0][q], w1v = wv[1][q], w2v = wv[2][q];
      v4h o0 = O4[2 * q], o1 = O4[2 * q + 1];
#pragma unroll
      for (int e = 0; e < 4; ++e) {
        v2h ap = ext8(av, e);
        a0 = fdot2f(ext8(w0v, e), ap, a0);
        a1 = fdot2f(ext8(w1v, e), ap, a1);
        a2 = fdot2f(ext8(w2v, e), ap, a2);
        v2h op = (e < 2) ? ext4(o0, e) : ext4(o1, e - 2);
        a3 = fdot2f(op, ap, a3);
      }
    }
    a0 += __shfl_xor(a0, 1);
    a1 += __shfl_xor(a1, 1);
    a2 += __shfl_xor(a2, 1);
    a3 += __shfl_xor(a3, 1);
    float gi = sigm(a0 + x0);
    float gf = sigm(a1 + x1);
    float gg = tanh_f(a2 + x2);
    float go = sigm(a3 + x3);
    c = gf * c + gi * gg;
    float h = go * tanh_f(c);
    __syncthreads();
    if (hf == 0) {
      ah[p] = (_Float16)h;
      if (h_out) h_out[((size_t)b * T + t) * H_ + p] = h;
    }
    __syncthreads();
  }
  if (c_out && hf == 0) c_out[(size_t)b * H_ + p] = c;
}

// ---------------------------------------------------------------------------
extern "C" void kernel_launch(void* const* d_in, const int* in_sizes, int n_in,
                              void* d_out, int out_size, void* d_ws, size_t ws_size,
                              hipStream_t stream) {
  const float* inp    = (const float*)d_in[0];
  const float* oe_wih = (const float*)d_in[1];
  const float* oe_whh = (const float*)d_in[2];
  const float* oe_bih = (const float*)d_in[3];
  const float* oe_bhh = (const float*)d_in[4];
  const float* ie_wih = (const float*)d_in[5];
  const float* ie_whh = (const float*)d_in[6];
  const float* ie_bih = (const float*)d_in[7];
  const float* ie_bhh = (const float*)d_in[8];
  const float* id_wih = (const float*)d_in[9];
  const float* id_whh = (const float*)d_in[10];
  const float* id_bih = (const float*)d_in[11];
  const float* id_bhh = (const float*)d_in[12];
  const float* od_wih = (const float*)d_in[13];
  const float* od_whh = (const float*)d_in[14];
  const float* od_bih = (const float*)d_in[15];
  const float* od_bhh = (const float*)d_in[16];

  char* ws = (char*)d_ws;
  _Float16* xT     = (_Float16*)(ws + 0);         // 76800*128 f16 = 19,660,800
  v8h* wpack_oe    = (v8h*)(ws + 19660800);       // 12*64*64*16  =    786,432
  float* cst       = (float*)(ws + 20447232);     // 3200*256*4   =  3,276,800
  v2h* wt2_ie      = (v2h*)(ws + 23724032);       // 128*1024*4   =    524,288
  float* xw_ie     = (float*)(ws + 24248320);     // 3200*1024*4  = 13,107,200
  _Float16* whh_ie = (_Float16*)(ws + 37355520);  // 262144 f16   =    524,288
  float* bott      = (float*)(ws + 37879808);     // 32*256*4     =     32,768
  v2h* wt2_id      = (v2h*)(ws + 37912576);       //              =    524,288
  float* xw_id     = (float*)(ws + 38436864);     // 32*1024*4    =    131,072
  _Float16* whh_id = (_Float16*)(ws + 38567936);  //              =    524,288
  float* dec       = (float*)(ws + 39092224);     // 3200*256*4   =  3,276,800
  v2h* wt2_odih    = (v2h*)(ws + 42369024);       // 128*512*4    =    262,144
  float* xw_od     = (float*)(ws + 42631168);     // 3200*512*4   =  6,553,600
  v8h* wpack_od    = (v8h*)(ws + 49184768);       // 4*32*64*16   =    131,072
  float* rec       = (float*)(ws + 49315840);     // 76800*128*4  = 39,321,600  (end 88.6 MB)

  // --- weight prep ---
  k_wpack_oe<<<dim3(192), dim3(256), 0, stream>>>(wpack_oe, oe_wih, oe_whh);
  k_wt2<<<dim3(512), dim3(256), 0, stream>>>(wt2_ie, ie_wih, 256, nullptr, 0, 1024, 128 * 1024);
  k_wt2<<<dim3(512), dim3(256), 0, stream>>>(wt2_id, id_wih, 256, nullptr, 0, 1024, 128 * 1024);
  k_wt2<<<dim3(256), dim3(256), 0, stream>>>(wt2_odih, od_wih, 256, nullptr, 0, 512, 128 * 512);
  k_wpack_od<<<dim3(32), dim3(256), 0, stream>>>(wpack_od, od_whh);
  k_f16<<<dim3(1024), dim3(256), 0, stream>>>(whh_ie, ie_whh, 262144);
  k_f16<<<dim3(1024), dim3(256), 0, stream>>>(whh_id, id_whh, 262144);

  // --- pipeline ---
  k_tin<<<dim3(75, 4, 32), dim3(32, 8), 0, stream>>>(inp, xT);
  k_outer_enc_mfma<<<dim3(100), dim3(512), 0, stream>>>(wpack_oe, xT, oe_bih, oe_bhh, cst);
  k_proj<4><<<dim3(200), dim3(256), 0, stream>>>(cst, wt2_ie, ie_bih, ie_bhh, xw_ie);
  k_inner<<<dim3(32), dim3(512), 0, stream>>>(whh_ie, xw_ie, (long)S_ * 1024, 1024, S_, nullptr, bott);
  k_proj<4><<<dim3(2), dim3(256), 0, stream>>>(bott, wt2_id, id_bih, id_bhh, xw_id);
  k_inner<<<dim3(32), dim3(512), 0, stream>>>(whh_id, xw_id, 1024, 0, S_, dec, nullptr);
  k_proj<2><<<dim3(200), dim3(256), 0, stream>>>(dec, wt2_odih, od_bih, od_bhh, xw_od);
  k_outer_dec_mfma<<<dim3(100), dim3(512), 0, stream>>>(wpack_od, xw_od, rec);
  k_tout<<<dim3(75, 4, 32), dim3(32, 8), 0, stream>>>(rec, (float*)d_out);

  (void)in_sizes; (void)n_in; (void)out_size; (void)ws_size;
}